// Round 15
// baseline (174.773 us; speedup 1.0000x reference)
//
#include <hip/hip_runtime.h>
#include <hip/hip_bf16.h>
#include <math.h>

#define DD 8192     // sketch dimension d
#define CC 768      // channels
#define SS 145      // sequence length
#define BB 32       // batch
#define SN 64       // sensor dim
#define SROWS 160   // padded s rows (10 tiles of 16)
#define NCKA 24     // A1u chunks (kA layout, 32 c each)

// ---- kD geometry ----
#define NETD 12          // e-tiles of 64
#define NCH 12           // chunks per block (one c-half)
#define M01W 36          // Mt01 row stride in u32 (144 B)
#define NWGD (BB*2*NETD) // 768 blocks

// ---- kZ geometry ----
#define ZT 512
#define NSL 16

typedef __attribute__((ext_vector_type(8))) short short8;   // 8 bf16
typedef __attribute__((ext_vector_type(4))) float f32x4;    // MFMA acc

__device__ __forceinline__ void gload16(const void* g, void* l) {
    __builtin_amdgcn_global_load_lds(
        (const __attribute__((address_space(1))) unsigned int*)g,
        (__attribute__((address_space(3))) unsigned int*)l, 16, 0, 0);
}

// ---------------------------------------------------------------------------
// kS: per-b sketch build (unchanged). u[b,c]=b_sen[c]+sensor·Wsen[c,:];
// CTG[b][c]=(u1, s1, bits(h1c), 0); P2G[b][t]=(S2u_b[t], S2s[t]).
// ---------------------------------------------------------------------------
__global__ __launch_bounds__(512) void kS(
    const float* __restrict__ sensor, const float* __restrict__ Wsen,
    const float* __restrict__ bsen,
    const int* __restrict__ h1, const int* __restrict__ h2,
    const int* __restrict__ s1, const int* __restrict__ s2,
    float4* __restrict__ CTG, float2* __restrict__ P2G)
{
    __shared__ float2 P2l[DD];
    __shared__ float  sens[SN];
    const int b   = blockIdx.x;
    const int tid = threadIdx.x;

    if (tid < SN) sens[tid] = sensor[b*SN + tid];
    {
        float4* p4 = (float4*)P2l;
        #pragma unroll
        for (int i = 0; i < 8; ++i) p4[tid + i*512] = make_float4(0.f,0.f,0.f,0.f);
    }
    __syncthreads();

    for (int c = tid; c < CC; c += 512) {
        float u = bsen[c];
        const float4* w = (const float4*)(Wsen + (size_t)c*SN);
        #pragma unroll
        for (int n4 = 0; n4 < 16; ++n4) {
            float4 wv = w[n4];
            u += sens[4*n4+0]*wv.x + sens[4*n4+1]*wv.y
               + sens[4*n4+2]*wv.z + sens[4*n4+3]*wv.w;
        }
        float f1 = (float)s1[c], f2 = (float)s2[c];
        float4 ct;
        ct.x = u * f1; ct.y = f1; ct.z = __int_as_float(h1[c]); ct.w = 0.f;
        CTG[(size_t)b*CC + c] = ct;
        int t = h2[c];
        unsafeAtomicAdd(&P2l[t].x, u * f2);
        unsafeAtomicAdd(&P2l[t].y, f2);
    }
    __syncthreads();

    {
        const float4* p4 = (const float4*)P2l;
        float4* dst = (float4*)(P2G + (size_t)b*DD);
        #pragma unroll
        for (int i = 0; i < 8; ++i) dst[tid + i*512] = p4[tid + i*512];
    }
}

// ---------------------------------------------------------------------------
// kZ: shifted-sketch Z build. Writes ZP[b][d] = pack(bf16 Zuu, bf16 Zcr);
// b==0 blocks also compute+write Z11b (others skip that FMA).
// ---------------------------------------------------------------------------
__global__ __launch_bounds__(ZT) void kZ(
    const float4* __restrict__ CTG, const float2* __restrict__ P2G,
    unsigned int* __restrict__ ZP, unsigned short* __restrict__ Z11b)
{
    __shared__ float2 P2l[DD];        // 64 KB

    const int bid = blockIdx.x;
    const int wg  = (bid & 7)*(BB*NSL/8) + (bid >> 3);
    const int b   = wg >> 4;
    const int dsl = wg & (NSL-1);
    const int tid = threadIdx.x;
    const bool doZ11 = (b == 0);

    {
        const float4* src = (const float4*)(P2G + (size_t)b*DD);
        float4* dst = (float4*)P2l;
        #pragma unroll
        for (int i = 0; i < 8; ++i) dst[tid + i*ZT] = src[tid + i*ZT];
    }
    __syncthreads();

    const int d = dsl*ZT + tid;
    const float4* ctp = CTG + (size_t)b*CC;
    float accU = 0.f, accC = 0.f, acc1 = 0.f;
    #pragma unroll 4
    for (int c = 0; c < CC; ++c) {
        float4 ct = ctp[c];
        int idx = (d - __float_as_int(ct.z)) & (DD-1);
        float2 p = P2l[idx];
        accU = fmaf(ct.x, p.x, accU);
        accC = fmaf(ct.x, p.y, fmaf(ct.y, p.x, accC));
        if (doZ11) acc1 = fmaf(ct.y, p.y, acc1);
    }

    __hip_bfloat16 zu = __float2bfloat16(accU);
    __hip_bfloat16 zc = __float2bfloat16(accC);
    ZP[(size_t)b*DD + d] = (unsigned int)*(unsigned short*)&zu
                         | ((unsigned int)*(unsigned short*)&zc << 16);
    if (doZ11) {
        __hip_bfloat16 z1 = __float2bfloat16(acc1);
        Z11b[d] = *(unsigned short*)&z1;
    }
}

// ---------------------------------------------------------------------------
// kA: A-panel, chunk-major swizzled (unchanged):
//   A1u[b][ck][row][16 u32], word (row,c2) at granule g'=(c2>>2)^(row&3).
// ---------------------------------------------------------------------------
__global__ __launch_bounds__(384) void kA(
    const float* __restrict__ E, const float* __restrict__ tok,
    const int* __restrict__ s1, unsigned int* __restrict__ A1u)
{
    const int b  = blockIdx.x;
    const int r0 = blockIdx.y * 16;
    const int p  = threadIdx.x;
    const int c  = 2*p;
    const int ck = p >> 4;
    const int c2 = p & 15;
    const float s1a = (float)s1[c], s1b = (float)s1[c+1];
    const float ta = tok[CC + c] * s1a, tb = tok[CC + c + 1] * s1b;
    #pragma unroll
    for (int rr = 0; rr < 16; ++rr) {
        int row = r0 + rr;
        unsigned int word = 0;
        if (row < SS) {
            float2 ev = *(const float2*)&E[((size_t)b*SS + row)*CC + c];
            __hip_bfloat16 x0 = __float2bfloat16(ev.x*s1a + ta);
            __hip_bfloat16 x1 = __float2bfloat16(ev.y*s1b + tb);
            word = (unsigned int)*(unsigned short*)&x0
                 | ((unsigned int)*(unsigned short*)&x1 << 16);
        }
        int gp = (c2 >> 2) ^ (row & 3);
        A1u[((size_t)(b*NCKA + ck)*SROWS + row)*16 + gp*4 + (c2 & 3)] = word;
    }
}

// ---------------------------------------------------------------------------
// kM11: materialize the b-INDEPENDENT m=2 matrix once (unchanged):
//   M11[ck][e][c2] = Z11[(h1[ck*32+c]+h2[e]) & 8191], bf16.
// ---------------------------------------------------------------------------
__global__ __launch_bounds__(512) void kM11(
    const unsigned short* __restrict__ Z11b,
    const int* __restrict__ h1, const int* __restrict__ h2,
    unsigned int* __restrict__ M11u)
{
    __shared__ unsigned short Z11l[DD];   // 16 KB
    const int ck  = blockIdx.x;
    const int tid = threadIdx.x;
    {
        const uint4* src = (const uint4*)Z11b;
        uint4* dst = (uint4*)Z11l;
        #pragma unroll
        for (int i = 0; i < 2; ++i) dst[tid + i*512] = src[tid + i*512];
    }
    __syncthreads();

    const int hA = h1[ck*32 + 2*(tid & 15)];
    const int hB = h1[ck*32 + 2*(tid & 15) + 1];
    const int cp = tid & 15;
    #pragma unroll 4
    for (int i = 0; i < 24; ++i) {
        int idx = tid + i*512;
        int ep  = idx >> 4;
        int cpp = idx & 15;
        int ha = (cpp == cp) ? hA : h1[ck*32 + 2*cpp];
        int hb = (cpp == cp) ? hB : h1[ck*32 + 2*cpp + 1];
        int he = h2[ep];
        unsigned int lo = Z11l[(ha + he) & (DD-1)];
        unsigned int hi = Z11l[(hb + he) & (DD-1)];
        M11u[((size_t)ck*768 + ep)*16 + cpp] = lo | (hi << 16);
    }
}

// ---------------------------------------------------------------------------
// kD: fused 3-form MFMA, m97-geometry: SINGLE-buffered Lt/Mt01 -> LDS
// 53760 B -> 3 blocks/CU (24 waves); 2 barriers/chunk; inter-block phase
// offset provides the stage/compute overlap (m97/m114 pattern).
// Block=(b, c-half, et64). 8 waves = 4 e-subs x 2 s-halves; 15 MFMA/chunk.
//  - A: global_load_lds DMA from swizzled A1u.
//  - m0,m1: one u32 gather/(c,e) from packed ZPl; unpack in VALU.
//  - m2: bfrag direct from L2-hot M11 (register, loaded at stage time).
// Epilogue: qv = (w2^2 a0 + w2 bb a1 + bb^2 a2)*a2v, one reduce+atomic.
// ---------------------------------------------------------------------------
__global__ __launch_bounds__(512, 4) void kD(
    const unsigned int* __restrict__ A1u,
    const unsigned short* __restrict__ M11,
    const float* __restrict__ E, const float* __restrict__ tok,
    const int* __restrict__ h1, const int* __restrict__ h2,
    const int* __restrict__ s2,
    const float* __restrict__ Ws2, const float* __restrict__ bs2,
    const unsigned int* __restrict__ ZP, float* __restrict__ Q)
{
    __shared__ __align__(16) unsigned int   ZPl[DD];        // 32768 B
    __shared__ __align__(16) unsigned short Lt[SROWS*32];   // 10240 B
    __shared__ __align__(16) unsigned int   Mt01[64*M01W];  //  9216 B
    __shared__ unsigned short h1l[CC];                      //  1536 B
    // total 53760 B -> 3 blocks/CU

    const int bid = blockIdx.x;
    const int wg  = (bid & 7)*(NWGD/8) + (bid >> 3);
    const int b   = wg / 24;
    const int r   = wg % 24;
    const int ch  = r / 12;
    const int et  = r % 12;
    const int tid = threadIdx.x;
    const int e0  = et * 64;
    const int cb0 = ch * 384;

    {
        const uint4* src = (const uint4*)(ZP + (size_t)b*DD);
        uint4* dst = (uint4*)ZPl;
        #pragma unroll
        for (int i = 0; i < 4; ++i) dst[tid + i*512] = src[tid + i*512];
    }
    for (int c = tid; c < CC; c += 512) h1l[c] = (unsigned short)h1[c];

    const int lane = tid & 63;
    const int wv   = tid >> 6;
    const int esub = wv & 3;
    const int shf  = wv >> 2;         // s-half
    const int l15  = lane & 15;
    const int l4   = lane >> 4;
    const int eg   = e0 + esub*16 + l15;

    int gh2[4];
    #pragma unroll
    for (int j = 0; j < 4; ++j) gh2[j] = h2[e0 + ((tid + j*512) >> 5)];
    __syncthreads();

    const char* Abase = (const char*)A1u + (size_t)b*NCKA*SROWS*64;

#define STAGE_A(K) { \
    const char* cbase = Abase + (size_t)(ch*NCH + (K))*SROWS*64; \
    gload16(cbase + wv*1024 + lane*16, (char*)Lt + wv*1024); \
    if (wv < 2) \
        gload16(cbase + 8192 + wv*1024 + lane*16, \
                (char*)Lt + 8192 + wv*1024); \
    }

#define GATHER(K) { \
    _Pragma("unroll") \
    for (int j = 0; j < 4; ++j) { \
        int idx = tid + j*512; \
        int ge = idx >> 5, gc = idx & 31; \
        int ad = ((int)h1l[cb0 + (K)*32 + gc] + gh2[j]) & (DD-1); \
        Mt01[ge*M01W + gc] = ZPl[ad]; \
    } }

#define LOADB2(K) \
    (*(const short8*)&M11[((size_t)(ch*NCH + (K))*768 + eg)*32 + l4*8])

#define MFMA_STEP(BQ) { \
    const unsigned int* mp = &Mt01[(esub*16 + l15)*M01W + l4*8]; \
    uint4 p0 = *(const uint4*)mp; \
    uint4 p1 = *(const uint4*)(mp + 4); \
    union { unsigned int u[4]; short8 s; } b0, b1; \
    b0.u[0] = (p0.x & 0xffffu) | (p0.y << 16); \
    b1.u[0] = (p0.x >> 16)     | (p0.y & 0xffff0000u); \
    b0.u[1] = (p0.z & 0xffffu) | (p0.w << 16); \
    b1.u[1] = (p0.z >> 16)     | (p0.w & 0xffff0000u); \
    b0.u[2] = (p1.x & 0xffffu) | (p1.y << 16); \
    b1.u[2] = (p1.x >> 16)     | (p1.y & 0xffff0000u); \
    b0.u[3] = (p1.z & 0xffffu) | (p1.w << 16); \
    b1.u[3] = (p1.z >> 16)     | (p1.w & 0xffff0000u); \
    __builtin_amdgcn_s_setprio(1); \
    _Pragma("unroll") \
    for (int t = 0; t < 5; ++t) { \
        int R = shf*80 + t*16 + l15; \
        short8 af = *(const short8*)&Lt[R*32 + ((l4 ^ (R & 3))*8)]; \
        acc0[t] = __builtin_amdgcn_mfma_f32_16x16x32_bf16(af, b0.s, acc0[t], 0,0,0); \
        acc1[t] = __builtin_amdgcn_mfma_f32_16x16x32_bf16(af, b1.s, acc1[t], 0,0,0); \
        acc2[t] = __builtin_amdgcn_mfma_f32_16x16x32_bf16(af, BQ,   acc2[t], 0,0,0); \
    } \
    __builtin_amdgcn_s_setprio(0); \
    }

    f32x4 acc0[5], acc1[5], acc2[5];
    #pragma unroll
    for (int t = 0; t < 5; ++t) {
        acc0[t] = (f32x4){0.f,0.f,0.f,0.f};
        acc1[t] = (f32x4){0.f,0.f,0.f,0.f};
        acc2[t] = (f32x4){0.f,0.f,0.f,0.f};
    }

    short8 bq;
    STAGE_A(0)
    GATHER(0)
    bq = LOADB2(0);
    __syncthreads();

    #pragma unroll 1
    for (int k = 0; k < NCH; ++k) {
        MFMA_STEP(bq)
        __syncthreads();              // all reads of Lt/Mt01 complete
        if (k + 1 < NCH) {
            STAGE_A(k + 1)
            GATHER(k + 1)
            bq = LOADB2(k + 1);
            __syncthreads();          // staging complete
        }
    }
#undef STAGE_A
#undef GATHER
#undef LOADB2
#undef MFMA_STEP

    // --- epilogue: combine 3 forms, reduce 16 e-lanes, one atomic ---
    const float s2e = (float)s2[eg];
    const float t2e = tok[CC + eg] * s2e;
    #pragma unroll
    for (int t = 0; t < 5; ++t) {
        #pragma unroll
        for (int rr = 0; rr < 4; ++rr) {
            int s = shf*80 + t*16 + l4*4 + rr;
            float qv = 0.f;
            if (s < SS) {
                float a2v = E[((size_t)b*SS + s)*CC + eg] * s2e + t2e;
                float w2v = Ws2[s], bbv = bs2[s];
                qv = (w2v*w2v*acc0[t][rr] + w2v*bbv*acc1[t][rr]
                      + bbv*bbv*acc2[t][rr]) * a2v;
            }
            qv += __shfl_xor(qv, 1);
            qv += __shfl_xor(qv, 2);
            qv += __shfl_xor(qv, 4);
            qv += __shfl_xor(qv, 8);
            if (l15 == 0 && s < SS)
                unsafeAtomicAdd(&Q[b*SS + s], qv);
        }
    }
}

// ---------------------------------------------------------------------------
// kE: bp = sign(Q)*sqrt(|Q|+1e-5); L2-normalize over s; project W_out.
// ---------------------------------------------------------------------------
__global__ __launch_bounds__(256) void kE(
    const float* __restrict__ Q, const float* __restrict__ Wout,
    const float* __restrict__ bout, float* __restrict__ out)
{
    __shared__ float red[8];
    const int b = blockIdx.x, tid = threadIdx.x;
    float v = 0.f, w = 0.f;
    if (tid < SS) {
        float ip = Q[b*SS + tid];
        float sg = (ip > 0.f) ? 1.f : ((ip < 0.f) ? -1.f : 0.f);
        v = sg * sqrtf(fabsf(ip) + 1e-5f);
        w = v * Wout[tid];
    }
    float sq = v * v;
    #pragma unroll
    for (int off = 32; off > 0; off >>= 1) {
        sq += __shfl_down(sq, off, 64);
        w  += __shfl_down(w,  off, 64);
    }
    if ((tid & 63) == 0) { red[tid >> 6] = sq; red[4 + (tid >> 6)] = w; }
    __syncthreads();
    if (tid == 0) {
        float ssq  = red[0] + red[1] + red[2] + red[3];
        float sw   = red[4] + red[5] + red[6] + red[7];
        float norm = fmaxf(sqrtf(ssq), 1e-12f);
        out[b] = sw / norm + bout[0];
    }
}

// ---------------------------------------------------------------------------
extern "C" void kernel_launch(void* const* d_in, const int* in_sizes, int n_in,
                              void* d_out, int out_size, void* d_ws, size_t ws_size,
                              hipStream_t stream) {
    const float* sensor = (const float*)d_in[0];
    const float* E      = (const float*)d_in[1];
    const int*   h1     = (const int*)d_in[3];
    const int*   h2     = (const int*)d_in[4];
    const int*   s1     = (const int*)d_in[5];
    const int*   s2     = (const int*)d_in[6];
    const float* Wsen   = (const float*)d_in[8];
    const float* bsen   = (const float*)d_in[9];
    const float* Ws2    = (const float*)d_in[10];
    const float* bs2    = (const float*)d_in[11];
    const float* Wout   = (const float*)d_in[12];
    const float* bout   = (const float*)d_in[13];
    const float* tok    = (const float*)d_in[14];
    float* out = (float*)d_out;

    // ws (~9.7 MB): phase1 CTG+P2G in [0,2.5M); kA's A1u overwrites [0,7.86M).
    // Non-aliased tail: ZP (1 MB) + Z11b (16 KB) + M11 (1.18 MB) + Q.
    char* ws = (char*)d_ws;
    float4* CTG = (float4*)ws;
    float2* P2G = (float2*)(ws + (size_t)BB*CC*16);
    unsigned int* A1u = (unsigned int*)ws;
    const size_t A1_BYTES = (size_t)BB*NCKA*SROWS*64;          // 7,864,320
    unsigned int*   ZP   = (unsigned int*)(ws + A1_BYTES);
    unsigned short* Z11b = (unsigned short*)(ws + A1_BYTES + (size_t)BB*DD*4);
    unsigned int*   M11u = (unsigned int*)((char*)Z11b + (size_t)DD*2);
    float* Q = (float*)((char*)M11u + (size_t)NCKA*768*32*2);

    hipMemsetAsync(Q, 0, (size_t)BB*SS*sizeof(float), stream);

    kS<<<dim3(BB), dim3(512), 0, stream>>>(
        sensor, Wsen, bsen, h1, h2, s1, s2, CTG, P2G);

    kZ<<<dim3(BB*NSL), dim3(ZT), 0, stream>>>(CTG, P2G, ZP, Z11b);

    // kA overwrites CTG/P2G (ordered after kZ on the same stream)
    kA<<<dim3(BB, SROWS/16), dim3(384), 0, stream>>>(E, tok, s1, A1u);

    kM11<<<dim3(NCKA), dim3(512), 0, stream>>>(Z11b, h1, h2, M11u);

    kD<<<dim3(NWGD), dim3(512), 0, stream>>>(
        A1u, (const unsigned short*)M11u, E, tok, h1, h2, s2, Ws2, bs2, ZP, Q);

    kE<<<dim3(BB), dim3(256), 0, stream>>>(Q, Wout, bout, out);
}